// Round 1
// baseline (1601.110 us; speedup 1.0000x reference)
//
#include <hip/hip_runtime.h>
#include <hip/hip_bf16.h>

#define B_ 4
#define N_ 65536
#define Q_ 400
#define C_ 20
#define M_ 64
#define QT 64
#define CHUNK 1024
#define NCHUNK (N_ / CHUNK)
#define NQT ((Q_ + QT - 1) / QT)

// ---------------- Kernel A: per-(b,m) stats: count + max(seg) (= class label) ----
__global__ __launch_bounds__(256) void stats_kernel(const int* __restrict__ inst,
                                                    const int* __restrict__ seg,
                                                    int* __restrict__ cnt_g,
                                                    int* __restrict__ smax_g) {
    int b = blockIdx.x >> 4;       // 16 chunks per batch
    int chunk = blockIdx.x & 15;
    __shared__ int scnt[M_];
    __shared__ int smax[M_];
    int tid = threadIdx.x;
    if (tid < M_) { scnt[tid] = 0; smax[tid] = 0; }
    __syncthreads();
    int base = b * N_ + chunk * 4096;
    for (int i = 0; i < 4096; i += 256) {
        int m = inst[base + tid + i];
        int s = seg[base + tid + i];
        atomicAdd(&scnt[m], 1);
        atomicMax(&smax[m], s);
    }
    __syncthreads();
    if (tid < M_) {
        atomicAdd(&cnt_g[b * M_ + tid], scnt[tid]);
        atomicMax(&smax_g[b * M_ + tid], smax[tid]);
    }
}

// ---------------- Kernel B: main binning over the mask logits ----------------
// Per block: one (b, q-tile of 64, n-chunk of 1024).
// Wave layout: lane = r*16 + c ; c in [0,16) covers q0=4c..4c+3 (float4 load),
// r in [0,4) covers 4 consecutive n rows -> 1 KB coalesced per wave load.
__global__ __launch_bounds__(256) void bin_kernel(const float* __restrict__ mask,
                                                  const int* __restrict__ inst,
                                                  float* __restrict__ xsum,
                                                  float* __restrict__ ssum,
                                                  float* __restrict__ negsum) {
    int chunk = blockIdx.x, qt = blockIdx.y, b = blockIdx.z;
    int qbase = qt * QT;
    __shared__ float xs[M_][QT + 1];   // +1 pad: bank = (m+q) % 32
    __shared__ float ss[M_][QT + 1];
    __shared__ int linst[CHUNK];
    int tid = threadIdx.x;
    for (int i = tid; i < M_ * (QT + 1); i += 256) {
        (&xs[0][0])[i] = 0.f;
        (&ss[0][0])[i] = 0.f;
    }
    // stage instance ids for this chunk (256 threads x int4 = 1024 ints)
    const int4* ip = (const int4*)(inst + b * N_ + chunk * CHUNK);
    ((int4*)linst)[tid] = ip[tid];
    __syncthreads();

    int lane = tid & 63, wave = tid >> 6;
    int r = lane >> 4, c = lane & 15;
    int q0 = qbase + 4 * c;
    bool qok = (q0 < Q_);
    int lq = 4 * c;

    float n0 = 0.f, n1 = 0.f, n2 = 0.f, n3 = 0.f;  // softplus accumulators per q
    int lnbase = wave * 4 + r;
    const float* mbase = mask + ((size_t)b * N_ + (size_t)chunk * CHUNK) * Q_ + q0;

    for (int i = 0; i < CHUNK / 16; ++i) {
        int ln = lnbase + i * 16;
        int m = linst[ln];
        if (qok) {
            float4 x = *(const float4*)(mbase + (size_t)ln * Q_);
            float e, sg;
            e = __expf(x.x); sg = __fdividef(e, 1.f + e);
            atomicAdd(&xs[m][lq + 0], x.x); atomicAdd(&ss[m][lq + 0], sg);
            n0 += __logf(1.f + e);
            e = __expf(x.y); sg = __fdividef(e, 1.f + e);
            atomicAdd(&xs[m][lq + 1], x.y); atomicAdd(&ss[m][lq + 1], sg);
            n1 += __logf(1.f + e);
            e = __expf(x.z); sg = __fdividef(e, 1.f + e);
            atomicAdd(&xs[m][lq + 2], x.z); atomicAdd(&ss[m][lq + 2], sg);
            n2 += __logf(1.f + e);
            e = __expf(x.w); sg = __fdividef(e, 1.f + e);
            atomicAdd(&xs[m][lq + 3], x.w); atomicAdd(&ss[m][lq + 3], sg);
            n3 += __logf(1.f + e);
        }
    }

    // reduce softplus partials across the 4 r-groups (lanes c, c+16, c+32, c+48)
    n0 += __shfl_xor(n0, 16); n0 += __shfl_xor(n0, 32);
    n1 += __shfl_xor(n1, 16); n1 += __shfl_xor(n1, 32);
    n2 += __shfl_xor(n2, 16); n2 += __shfl_xor(n2, 32);
    n3 += __shfl_xor(n3, 16); n3 += __shfl_xor(n3, 32);
    if (r == 0 && qok) {
        atomicAdd(&negsum[b * Q_ + q0 + 0], n0);
        atomicAdd(&negsum[b * Q_ + q0 + 1], n1);
        atomicAdd(&negsum[b * Q_ + q0 + 2], n2);
        atomicAdd(&negsum[b * Q_ + q0 + 3], n3);
    }
    __syncthreads();

    // flush bins to global (m fastest -> coalesced atomics)
    for (int idx = tid; idx < M_ * QT; idx += 256) {
        int m = idx & (M_ - 1);
        int lqq = idx >> 6;
        int q = qbase + lqq;
        if (q < Q_) {
            atomicAdd(&xsum[((b * Q_ + q) << 6) + m], xs[m][lqq]);
            atomicAdd(&ssum[((b * Q_ + q) << 6) + m], ss[m][lqq]);
        }
    }
}

// ---------------- Kernel C: finalize cost[b][q][m] --------------------------
__global__ __launch_bounds__(64) void final_kernel(const float* __restrict__ cls_in,
                                                   const float* __restrict__ xsum,
                                                   const float* __restrict__ ssum,
                                                   const float* __restrict__ negsum,
                                                   const int* __restrict__ cnt_g,
                                                   const int* __restrict__ smax_g,
                                                   float* __restrict__ out) {
    int bq = blockIdx.x;
    int b = bq / Q_;
    int m = threadIdx.x;
    float Xs = xsum[(bq << 6) + m];
    float Ss = ssum[(bq << 6) + m];
    float sigsum = Ss;  // sum over m == sum over all n (every point has an instance)
    for (int off = 32; off; off >>= 1) sigsum += __shfl_xor(sigsum, off);

    __shared__ float cls[C_];
    if (m < C_) cls[m] = cls_in[bq * C_ + m];
    __syncthreads();
    float mx = cls[0];
    for (int i = 1; i < C_; ++i) mx = fmaxf(mx, cls[i]);
    float se = 0.f;
    for (int i = 0; i < C_; ++i) se += __expf(cls[i] - mx);
    int label = smax_g[b * M_ + m];
    float p = __expf(cls[label] - mx) / se;

    float cm = (negsum[bq] - Xs) * (1.f / (float)N_);
    float cd = 1.f - (2.f * Ss + 1.f) / (sigsum + (float)cnt_g[b * M_ + m] + 1.f);
    out[(bq << 6) + m] = cm + (1.f - p) + cd;
}

extern "C" void kernel_launch(void* const* d_in, const int* in_sizes, int n_in,
                              void* d_out, int out_size, void* d_ws, size_t ws_size,
                              hipStream_t stream) {
    const float* mask = (const float*)d_in[0];   // [B, N, Q] f32
    const float* cls  = (const float*)d_in[1];   // [B, Q, C] f32
    const int*   inst = (const int*)d_in[2];     // [B, N] i32
    const int*   seg  = (const int*)d_in[3];     // [B, N] i32
    float* out = (float*)d_out;                  // [B, Q, M] f32

    float* xsum   = (float*)d_ws;                // B*Q*M
    float* ssum   = xsum + B_ * Q_ * M_;         // B*Q*M
    float* negsum = ssum + B_ * Q_ * M_;         // B*Q
    int*   cnt_g  = (int*)(negsum + B_ * Q_);    // B*M
    int*   smax_g = cnt_g + B_ * M_;             // B*M

    size_t zbytes = (size_t)(2 * B_ * Q_ * M_ + B_ * Q_ + 2 * B_ * M_) * 4;
    hipMemsetAsync(d_ws, 0, zbytes, stream);

    stats_kernel<<<B_ * 16, 256, 0, stream>>>(inst, seg, cnt_g, smax_g);
    bin_kernel<<<dim3(NCHUNK, NQT, B_), 256, 0, stream>>>(mask, inst, xsum, ssum, negsum);
    final_kernel<<<B_ * Q_, 64, 0, stream>>>(cls, xsum, ssum, negsum, cnt_g, smax_g, out);
}

// Round 2
// 645.937 us; speedup vs baseline: 2.4787x; 2.4787x over previous
//
#include <hip/hip_runtime.h>
#include <hip/hip_bf16.h>

#define B_ 4
#define N_ 65536
#define Q_ 400
#define C_ 20
#define M_ 64
#define QT 64
#define CHUNK 1024
#define NCHUNK (N_ / CHUNK)
#define NQT ((Q_ + QT - 1) / QT)

// fixed-point scales (int atomics are native; float atomics compile to CAS loops)
#define SX 8192.0f      // Xsum (raw logits) scale: 2^13
#define SS 32768.0f     // Ssum (sigmoid) scale: 2^15
#define SN 8192.0f      // negsum (softplus) scale: 2^13

// ---------------- Kernel A: per-(b,m) stats: count + max(seg) (= class label) ----
__global__ __launch_bounds__(256) void stats_kernel(const int* __restrict__ inst,
                                                    const int* __restrict__ seg,
                                                    int* __restrict__ cnt_g,
                                                    int* __restrict__ smax_g) {
    int b = blockIdx.x >> 4;       // 16 chunks per batch
    int chunk = blockIdx.x & 15;
    __shared__ int scnt[M_];
    __shared__ int smax[M_];
    int tid = threadIdx.x;
    if (tid < M_) { scnt[tid] = 0; smax[tid] = 0; }
    __syncthreads();
    int base = b * N_ + chunk * 4096;
    for (int i = 0; i < 4096; i += 256) {
        int m = inst[base + tid + i];
        int s = seg[base + tid + i];
        atomicAdd(&scnt[m], 1);
        atomicMax(&smax[m], s);
    }
    __syncthreads();
    if (tid < M_) {
        atomicAdd(&cnt_g[b * M_ + tid], scnt[tid]);
        atomicMax(&smax_g[b * M_ + tid], smax[tid]);
    }
}

// ---------------- Kernel B: main binning over the mask logits ----------------
// Per block: one (b, q-tile of 64, n-chunk of 1024).
// Wave layout: lane = r*16 + c ; c in [0,16) covers q0=4c..4c+3 (float4 load),
// r in [0,4) covers 4 consecutive n rows -> 1 KB coalesced per wave load.
__global__ __launch_bounds__(256) void bin_kernel(const float* __restrict__ mask,
                                                  const int* __restrict__ inst,
                                                  int* __restrict__ xsum,
                                                  int* __restrict__ ssum,
                                                  int* __restrict__ negsum) {
    int chunk = blockIdx.x, qt = blockIdx.y, b = blockIdx.z;
    int qbase = qt * QT;
    __shared__ int xs[M_][QT + 1];   // +1 pad: bank = (m+q) % 32
    __shared__ int ss[M_][QT + 1];
    __shared__ int linst[CHUNK];
    int tid = threadIdx.x;
    for (int i = tid; i < M_ * (QT + 1); i += 256) {
        (&xs[0][0])[i] = 0;
        (&ss[0][0])[i] = 0;
    }
    // stage instance ids for this chunk (256 threads x int4 = 1024 ints)
    const int4* ip = (const int4*)(inst + b * N_ + chunk * CHUNK);
    ((int4*)linst)[tid] = ip[tid];
    __syncthreads();

    int lane = tid & 63, wave = tid >> 6;
    int r = lane >> 4, c = lane & 15;
    int q0 = qbase + 4 * c;
    bool qok = (q0 < Q_);
    int lq = 4 * c;

    float n0 = 0.f, n1 = 0.f, n2 = 0.f, n3 = 0.f;  // softplus accumulators per q
    int lnbase = wave * 4 + r;
    const float* mbase = mask + ((size_t)b * N_ + (size_t)chunk * CHUNK) * Q_ + q0;

    for (int i = 0; i < CHUNK / 16; ++i) {
        int ln = lnbase + i * 16;
        int m = linst[ln];
        if (qok) {
            float4 x = *(const float4*)(mbase + (size_t)ln * Q_);
            float e, sg;
            e = __expf(x.x); sg = __fdividef(e, 1.f + e);
            atomicAdd(&xs[m][lq + 0], __float2int_rn(x.x * SX));
            atomicAdd(&ss[m][lq + 0], (int)__float2uint_rn(sg * SS));
            n0 += __logf(1.f + e);
            e = __expf(x.y); sg = __fdividef(e, 1.f + e);
            atomicAdd(&xs[m][lq + 1], __float2int_rn(x.y * SX));
            atomicAdd(&ss[m][lq + 1], (int)__float2uint_rn(sg * SS));
            n1 += __logf(1.f + e);
            e = __expf(x.z); sg = __fdividef(e, 1.f + e);
            atomicAdd(&xs[m][lq + 2], __float2int_rn(x.z * SX));
            atomicAdd(&ss[m][lq + 2], (int)__float2uint_rn(sg * SS));
            n2 += __logf(1.f + e);
            e = __expf(x.w); sg = __fdividef(e, 1.f + e);
            atomicAdd(&xs[m][lq + 3], __float2int_rn(x.w * SX));
            atomicAdd(&ss[m][lq + 3], (int)__float2uint_rn(sg * SS));
            n3 += __logf(1.f + e);
        }
    }

    // reduce softplus partials across the 4 r-groups (lanes c, c+16, c+32, c+48)
    n0 += __shfl_xor(n0, 16); n0 += __shfl_xor(n0, 32);
    n1 += __shfl_xor(n1, 16); n1 += __shfl_xor(n1, 32);
    n2 += __shfl_xor(n2, 16); n2 += __shfl_xor(n2, 32);
    n3 += __shfl_xor(n3, 16); n3 += __shfl_xor(n3, 32);
    if (r == 0 && qok) {
        atomicAdd(&negsum[b * Q_ + q0 + 0], __float2int_rn(n0 * SN));
        atomicAdd(&negsum[b * Q_ + q0 + 1], __float2int_rn(n1 * SN));
        atomicAdd(&negsum[b * Q_ + q0 + 2], __float2int_rn(n2 * SN));
        atomicAdd(&negsum[b * Q_ + q0 + 3], __float2int_rn(n3 * SN));
    }
    __syncthreads();

    // flush bins to global (m fastest -> coalesced atomics)
    for (int idx = tid; idx < M_ * QT; idx += 256) {
        int m = idx & (M_ - 1);
        int lqq = idx >> 6;
        int q = qbase + lqq;
        if (q < Q_) {
            atomicAdd(&xsum[((b * Q_ + q) << 6) + m], xs[m][lqq]);
            atomicAdd(&ssum[((b * Q_ + q) << 6) + m], ss[m][lqq]);
        }
    }
}

// ---------------- Kernel C: finalize cost[b][q][m] --------------------------
__global__ __launch_bounds__(64) void final_kernel(const float* __restrict__ cls_in,
                                                   const int* __restrict__ xsum,
                                                   const int* __restrict__ ssum,
                                                   const int* __restrict__ negsum,
                                                   const int* __restrict__ cnt_g,
                                                   const int* __restrict__ smax_g,
                                                   float* __restrict__ out) {
    int bq = blockIdx.x;
    int b = bq / Q_;
    int m = threadIdx.x;
    float Xs = (float)xsum[(bq << 6) + m] * (1.0f / SX);
    float Ss = (float)ssum[(bq << 6) + m] * (1.0f / SS);
    float sigsum = Ss;  // sum over m == sum over all n (every point has an instance)
    for (int off = 32; off; off >>= 1) sigsum += __shfl_xor(sigsum, off);

    __shared__ float cls[C_];
    if (m < C_) cls[m] = cls_in[bq * C_ + m];
    __syncthreads();
    float mx = cls[0];
    for (int i = 1; i < C_; ++i) mx = fmaxf(mx, cls[i]);
    float se = 0.f;
    for (int i = 0; i < C_; ++i) se += __expf(cls[i] - mx);
    int label = smax_g[b * M_ + m];
    float p = __expf(cls[label] - mx) / se;

    float negf = (float)negsum[bq] * (1.0f / SN);
    float cm = (negf - Xs) * (1.f / (float)N_);
    float cd = 1.f - (2.f * Ss + 1.f) / (sigsum + (float)cnt_g[b * M_ + m] + 1.f);
    out[(bq << 6) + m] = cm + (1.f - p) + cd;
}

extern "C" void kernel_launch(void* const* d_in, const int* in_sizes, int n_in,
                              void* d_out, int out_size, void* d_ws, size_t ws_size,
                              hipStream_t stream) {
    const float* mask = (const float*)d_in[0];   // [B, N, Q] f32
    const float* cls  = (const float*)d_in[1];   // [B, Q, C] f32
    const int*   inst = (const int*)d_in[2];     // [B, N] i32
    const int*   seg  = (const int*)d_in[3];     // [B, N] i32
    float* out = (float*)d_out;                  // [B, Q, M] f32

    int* xsum   = (int*)d_ws;                    // B*Q*M
    int* ssum   = xsum + B_ * Q_ * M_;           // B*Q*M
    int* negsum = ssum + B_ * Q_ * M_;           // B*Q
    int* cnt_g  = negsum + B_ * Q_;              // B*M
    int* smax_g = cnt_g + B_ * M_;               // B*M

    size_t zbytes = (size_t)(2 * B_ * Q_ * M_ + B_ * Q_ + 2 * B_ * M_) * 4;
    hipMemsetAsync(d_ws, 0, zbytes, stream);

    stats_kernel<<<B_ * 16, 256, 0, stream>>>(inst, seg, cnt_g, smax_g);
    bin_kernel<<<dim3(NCHUNK, NQT, B_), 256, 0, stream>>>(mask, inst, xsum, ssum, negsum);
    final_kernel<<<B_ * Q_, 64, 0, stream>>>(cls, xsum, ssum, negsum, cnt_g, smax_g, out);
}

// Round 3
// 644.086 us; speedup vs baseline: 2.4859x; 1.0029x over previous
//
#include <hip/hip_runtime.h>
#include <hip/hip_bf16.h>

#define B_ 4
#define N_ 65536
#define Q_ 400
#define C_ 20
#define M_ 64
#define QT 64
#define CHUNK 1024
#define NCHUNK (N_ / CHUNK)
#define NQT ((Q_ + QT - 1) / QT)

// fixed-point scales (int atomics are native; float atomics compile to CAS loops)
#define SX 8192.0f      // Xsum (raw logits) scale: 2^13
#define SS 32768.0f     // Ssum (sigmoid) scale: 2^15
#define SN 8192.0f      // negsum (softplus) scale: 2^13

// ---------------- Kernel A: per-(b,m) stats: count + max(seg) (= class label) ----
__global__ __launch_bounds__(256) void stats_kernel(const int* __restrict__ inst,
                                                    const int* __restrict__ seg,
                                                    int* __restrict__ cnt_g,
                                                    int* __restrict__ smax_g) {
    int b = blockIdx.x >> 4;       // 16 chunks per batch
    int chunk = blockIdx.x & 15;
    __shared__ int scnt[M_];
    __shared__ int smax[M_];
    int tid = threadIdx.x;
    if (tid < M_) { scnt[tid] = 0; smax[tid] = 0; }
    __syncthreads();
    int base = b * N_ + chunk * 4096;
    for (int i = 0; i < 4096; i += 256) {
        int m = inst[base + tid + i];
        int s = seg[base + tid + i];
        atomicAdd(&scnt[m], 1);
        atomicMax(&smax[m], s);
    }
    __syncthreads();
    if (tid < M_) {
        atomicAdd(&cnt_g[b * M_ + tid], scnt[tid]);
        atomicMax(&smax_g[b * M_ + tid], smax[tid]);
    }
}

// ---------------- Kernel B: main binning over the mask logits ----------------
// 512 threads = 8 waves/block; LDS 37.4 KB -> 4 blocks/CU -> 32 waves/CU (100% occ).
// Wave layout: lane = r*16 + c ; c in [0,16) covers q0=4c..4c+3 (float4 load),
// r in [0,4) covers 4 n rows. Unroll-2 over iterations with both loads up front.
__global__ __launch_bounds__(512) void bin_kernel(const float* __restrict__ mask,
                                                  const int* __restrict__ inst,
                                                  int* __restrict__ xsum,
                                                  int* __restrict__ ssum,
                                                  int* __restrict__ negsum) {
    int chunk = blockIdx.x, qt = blockIdx.y, b = blockIdx.z;
    int qbase = qt * QT;
    __shared__ int xs[M_][QT + 1];   // +1 pad: bank = (m+q) % 32
    __shared__ int ss[M_][QT + 1];
    __shared__ int linst[CHUNK];
    int tid = threadIdx.x;
    for (int i = tid; i < M_ * (QT + 1); i += 512) {
        (&xs[0][0])[i] = 0;
        (&ss[0][0])[i] = 0;
    }
    // stage instance ids for this chunk (512 threads x int2 = 1024 ints)
    const int2* ip = (const int2*)(inst + b * N_ + chunk * CHUNK);
    ((int2*)linst)[tid] = ip[tid];
    __syncthreads();

    int lane = tid & 63, wave = tid >> 6;
    int r = lane >> 4, c = lane & 15;
    int q0 = qbase + 4 * c;
    bool qok = (q0 < Q_);
    int lq = 4 * c;

    float n0 = 0.f, n1 = 0.f, n2 = 0.f, n3 = 0.f;  // softplus accumulators per q
    int lnbase = wave * 4 + r;                      // 8 waves x 4 r = 32 rows/pass
    const float* mbase = mask + ((size_t)b * N_ + (size_t)chunk * CHUNK) * Q_ + q0;

    if (qok) {
        for (int i = 0; i < CHUNK / 32; i += 2) {
            int ln0 = lnbase + i * 32;
            int ln1 = ln0 + 32;
            // issue both loads + both inst reads before any math
            float4 xa = *(const float4*)(mbase + (size_t)ln0 * Q_);
            float4 xb = *(const float4*)(mbase + (size_t)ln1 * Q_);
            int m0 = linst[ln0];
            int m1 = linst[ln1];

            float ea0 = __expf(xa.x), ea1 = __expf(xa.y), ea2 = __expf(xa.z), ea3 = __expf(xa.w);
            float eb0 = __expf(xb.x), eb1 = __expf(xb.y), eb2 = __expf(xb.z), eb3 = __expf(xb.w);
            float ta0 = 1.f + ea0, ta1 = 1.f + ea1, ta2 = 1.f + ea2, ta3 = 1.f + ea3;
            float tb0 = 1.f + eb0, tb1 = 1.f + eb1, tb2 = 1.f + eb2, tb3 = 1.f + eb3;
            float sa0 = ea0 * __builtin_amdgcn_rcpf(ta0);
            float sa1 = ea1 * __builtin_amdgcn_rcpf(ta1);
            float sa2 = ea2 * __builtin_amdgcn_rcpf(ta2);
            float sa3 = ea3 * __builtin_amdgcn_rcpf(ta3);
            float sb0 = eb0 * __builtin_amdgcn_rcpf(tb0);
            float sb1 = eb1 * __builtin_amdgcn_rcpf(tb1);
            float sb2 = eb2 * __builtin_amdgcn_rcpf(tb2);
            float sb3 = eb3 * __builtin_amdgcn_rcpf(tb3);

            atomicAdd(&xs[m0][lq + 0], __float2int_rn(xa.x * SX));
            atomicAdd(&xs[m0][lq + 1], __float2int_rn(xa.y * SX));
            atomicAdd(&xs[m0][lq + 2], __float2int_rn(xa.z * SX));
            atomicAdd(&xs[m0][lq + 3], __float2int_rn(xa.w * SX));
            atomicAdd(&ss[m0][lq + 0], (int)__float2uint_rn(sa0 * SS));
            atomicAdd(&ss[m0][lq + 1], (int)__float2uint_rn(sa1 * SS));
            atomicAdd(&ss[m0][lq + 2], (int)__float2uint_rn(sa2 * SS));
            atomicAdd(&ss[m0][lq + 3], (int)__float2uint_rn(sa3 * SS));
            atomicAdd(&xs[m1][lq + 0], __float2int_rn(xb.x * SX));
            atomicAdd(&xs[m1][lq + 1], __float2int_rn(xb.y * SX));
            atomicAdd(&xs[m1][lq + 2], __float2int_rn(xb.z * SX));
            atomicAdd(&xs[m1][lq + 3], __float2int_rn(xb.w * SX));
            atomicAdd(&ss[m1][lq + 0], (int)__float2uint_rn(sb0 * SS));
            atomicAdd(&ss[m1][lq + 1], (int)__float2uint_rn(sb1 * SS));
            atomicAdd(&ss[m1][lq + 2], (int)__float2uint_rn(sb2 * SS));
            atomicAdd(&ss[m1][lq + 3], (int)__float2uint_rn(sb3 * SS));

            n0 += __logf(ta0) + __logf(tb0);
            n1 += __logf(ta1) + __logf(tb1);
            n2 += __logf(ta2) + __logf(tb2);
            n3 += __logf(ta3) + __logf(tb3);
        }
    }

    // reduce softplus partials across the 4 r-groups (lanes c, c+16, c+32, c+48)
    n0 += __shfl_xor(n0, 16); n0 += __shfl_xor(n0, 32);
    n1 += __shfl_xor(n1, 16); n1 += __shfl_xor(n1, 32);
    n2 += __shfl_xor(n2, 16); n2 += __shfl_xor(n2, 32);
    n3 += __shfl_xor(n3, 16); n3 += __shfl_xor(n3, 32);
    if (r == 0 && qok) {
        atomicAdd(&negsum[b * Q_ + q0 + 0], __float2int_rn(n0 * SN));
        atomicAdd(&negsum[b * Q_ + q0 + 1], __float2int_rn(n1 * SN));
        atomicAdd(&negsum[b * Q_ + q0 + 2], __float2int_rn(n2 * SN));
        atomicAdd(&negsum[b * Q_ + q0 + 3], __float2int_rn(n3 * SN));
    }
    __syncthreads();

    // flush bins to global (m fastest -> coalesced atomics)
    for (int idx = tid; idx < M_ * QT; idx += 512) {
        int m = idx & (M_ - 1);
        int lqq = idx >> 6;
        int q = qbase + lqq;
        if (q < Q_) {
            atomicAdd(&xsum[((b * Q_ + q) << 6) + m], xs[m][lqq]);
            atomicAdd(&ssum[((b * Q_ + q) << 6) + m], ss[m][lqq]);
        }
    }
}

// ---------------- Kernel C: finalize cost[b][q][m] --------------------------
__global__ __launch_bounds__(64) void final_kernel(const float* __restrict__ cls_in,
                                                   const int* __restrict__ xsum,
                                                   const int* __restrict__ ssum,
                                                   const int* __restrict__ negsum,
                                                   const int* __restrict__ cnt_g,
                                                   const int* __restrict__ smax_g,
                                                   float* __restrict__ out) {
    int bq = blockIdx.x;
    int b = bq / Q_;
    int m = threadIdx.x;
    float Xs = (float)xsum[(bq << 6) + m] * (1.0f / SX);
    float Ss = (float)ssum[(bq << 6) + m] * (1.0f / SS);
    float sigsum = Ss;  // sum over m == sum over all n (every point has an instance)
    for (int off = 32; off; off >>= 1) sigsum += __shfl_xor(sigsum, off);

    __shared__ float cls[C_];
    if (m < C_) cls[m] = cls_in[bq * C_ + m];
    __syncthreads();
    float mx = cls[0];
    for (int i = 1; i < C_; ++i) mx = fmaxf(mx, cls[i]);
    float se = 0.f;
    for (int i = 0; i < C_; ++i) se += __expf(cls[i] - mx);
    int label = smax_g[b * M_ + m];
    float p = __expf(cls[label] - mx) / se;

    float negf = (float)negsum[bq] * (1.0f / SN);
    float cm = (negf - Xs) * (1.f / (float)N_);
    float cd = 1.f - (2.f * Ss + 1.f) / (sigsum + (float)cnt_g[b * M_ + m] + 1.f);
    out[(bq << 6) + m] = cm + (1.f - p) + cd;
}

extern "C" void kernel_launch(void* const* d_in, const int* in_sizes, int n_in,
                              void* d_out, int out_size, void* d_ws, size_t ws_size,
                              hipStream_t stream) {
    const float* mask = (const float*)d_in[0];   // [B, N, Q] f32
    const float* cls  = (const float*)d_in[1];   // [B, Q, C] f32
    const int*   inst = (const int*)d_in[2];     // [B, N] i32
    const int*   seg  = (const int*)d_in[3];     // [B, N] i32
    float* out = (float*)d_out;                  // [B, Q, M] f32

    int* xsum   = (int*)d_ws;                    // B*Q*M
    int* ssum   = xsum + B_ * Q_ * M_;           // B*Q*M
    int* negsum = ssum + B_ * Q_ * M_;           // B*Q
    int* cnt_g  = negsum + B_ * Q_;              // B*M
    int* smax_g = cnt_g + B_ * M_;               // B*M

    size_t zbytes = (size_t)(2 * B_ * Q_ * M_ + B_ * Q_ + 2 * B_ * M_) * 4;
    hipMemsetAsync(d_ws, 0, zbytes, stream);

    stats_kernel<<<B_ * 16, 256, 0, stream>>>(inst, seg, cnt_g, smax_g);
    bin_kernel<<<dim3(NCHUNK, NQT, B_), 512, 0, stream>>>(mask, inst, xsum, ssum, negsum);
    final_kernel<<<B_ * Q_, 64, 0, stream>>>(cls, xsum, ssum, negsum, cnt_g, smax_g, out);
}